// Round 1
// baseline (195.342 us; speedup 1.0000x reference)
//
#include <hip/hip_runtime.h>

// SubjectLayers: out[b,o,t] = sum_c W[subj[b],o,c] * x[b,c,t] + bias[subj[b],o]
// B=128, C=64, T=8192, S=16, all fp32.
//
// Strategy (R1): vector-fp32 register-tiled kernel.
//  - block = 256 threads, handles one (b, 256-wide t-chunk)
//  - thread = 16 outputs x 4 t (float4), 64 fp32 accumulators
//  - W[s] transposed into LDS -> per-c weights read as wave-uniform ds_read_b128
//  - x loads float4 coalesced; 4 o-group waves share addresses (L1 hits)

namespace {
constexpr int Cdim  = 64;
constexpr int Tdim  = 8192;
constexpr int TTILE = 256;   // t per block
constexpr int NT    = 4;     // t per thread (float4)
constexpr int OG    = 16;    // outputs per thread
constexpr int BLOCK = 256;
}

__global__ __launch_bounds__(BLOCK, 4)
void subject_layers_kernel(const float* __restrict__ x,
                           const int*   __restrict__ subj,
                           const float* __restrict__ W,
                           const float* __restrict__ bias,
                           float*       __restrict__ out) {
    __shared__ float Wt[Cdim][Cdim];   // Wt[c][o] = W[s][o][c]
    __shared__ float bsh[Cdim];

    const int b   = blockIdx.y;
    const int tid = threadIdx.x;
    const int s   = subj[b];

    // Stage W transposed (coalesced global read; LDS write conflicts are a
    // once-per-block cost, negligible vs the 4096-FMA main loop).
    const float* Ws = W + s * (Cdim * Cdim);
    #pragma unroll
    for (int i = 0; i < (Cdim * Cdim) / BLOCK; ++i) {
        const int idx = i * BLOCK + tid;
        const int o = idx >> 6;      // row of W
        const int c = idx & 63;      // col of W (contiguous in global)
        Wt[c][o] = Ws[idx];
    }
    if (tid < Cdim) bsh[tid] = bias[s * Cdim + tid];
    __syncthreads();

    const int lane = tid & 63;
    const int og   = tid >> 6;          // 0..3
    const int o0   = og * OG;
    const int t0   = blockIdx.x * TTILE + lane * NT;

    const float* xp = x + (size_t)b * (Cdim * Tdim) + t0;

    float acc[OG][NT];
    #pragma unroll
    for (int o = 0; o < OG; ++o) {
        const float bv = bsh[o0 + o];
        #pragma unroll
        for (int k = 0; k < NT; ++k) acc[o][k] = bv;
    }

    #pragma unroll 4
    for (int c = 0; c < Cdim; ++c) {
        const float4 xv = *reinterpret_cast<const float4*>(xp + c * Tdim);
        const float xs[NT] = {xv.x, xv.y, xv.z, xv.w};
        #pragma unroll
        for (int q = 0; q < OG / 4; ++q) {
            // wave-uniform address -> LDS broadcast, conflict-free
            const float4 w = *reinterpret_cast<const float4*>(&Wt[c][o0 + q * 4]);
            const float ws[4] = {w.x, w.y, w.z, w.w};
            #pragma unroll
            for (int j = 0; j < 4; ++j) {
                #pragma unroll
                for (int k = 0; k < NT; ++k) {
                    acc[q * 4 + j][k] = fmaf(ws[j], xs[k], acc[q * 4 + j][k]);
                }
            }
        }
    }

    float* op = out + (size_t)b * (Cdim * Tdim) + (size_t)o0 * Tdim + t0;
    #pragma unroll
    for (int o = 0; o < OG; ++o) {
        float4 v;
        v.x = acc[o][0]; v.y = acc[o][1]; v.z = acc[o][2]; v.w = acc[o][3];
        *reinterpret_cast<float4*>(op + (size_t)o * Tdim) = v;
    }
}

extern "C" void kernel_launch(void* const* d_in, const int* in_sizes, int n_in,
                              void* d_out, int out_size, void* d_ws, size_t ws_size,
                              hipStream_t stream) {
    const float* x    = (const float*)d_in[0];   // [B, C, T]
    const int*   subj = (const int*)  d_in[1];   // [B]
    const float* W    = (const float*)d_in[2];   // [S, C, C]
    const float* bias = (const float*)d_in[3];   // [S, C]
    float*       out  = (float*)d_out;           // [B, C, T]

    const int B = in_sizes[1];                   // 128
    dim3 grid(Tdim / TTILE, B);                  // (32, 128) = 4096 blocks
    dim3 block(BLOCK);
    hipLaunchKernelGGL(subject_layers_kernel, grid, block, 0, stream,
                       x, subj, W, bias, out);
}